// Round 6
// baseline (1236.746 us; speedup 1.0000x reference)
//
#include <hip/hip_runtime.h>
#include <hip/hip_bf16.h>
#include <math.h>

#ifndef M_PI
#define M_PI 3.14159265358979323846
#endif

typedef __attribute__((ext_vector_type(8))) short bf16x8;
typedef __attribute__((ext_vector_type(4))) float f32x4;

struct Filt { float f[12]; };

// ---------------------------------------------------------------------------
// Host-side kaiser-sinc filter (matches reference; FILT_UP == FILT_DOWN).
// ---------------------------------------------------------------------------
static double bessel_i0(double x) {
  double sum = 1.0, term = 1.0;
  for (int k = 1; k < 64; ++k) {
    term *= x / (2.0 * k);
    double t2 = term * term;
    sum += t2;
    if (t2 < 1e-22 * sum) break;
  }
  return sum;
}

static void compute_filter(float* out12) {
  const int ks = 12;
  const double cutoff = 0.25, half_width = 0.3;
  const int half_size = 6;
  double delta_f = 4.0 * half_width;
  double A = 2.285 * (half_size - 1) * M_PI * delta_f + 7.95;
  double beta;
  if (A > 50.0)       beta = 0.1102 * (A - 8.7);
  else if (A >= 21.0) beta = 0.5842 * pow(A - 21.0, 0.4) + 0.07886 * (A - 21.0);
  else                beta = 0.0;
  double i0b = bessel_i0(beta);
  double f[12], s = 0.0;
  for (int n = 0; n < ks; ++n) {
    double ratio = (n - (ks - 1) / 2.0) / ((ks - 1) / 2.0);
    double arg = 1.0 - ratio * ratio;
    double wnd = bessel_i0(beta * sqrt(arg > 0.0 ? arg : 0.0)) / i0b;
    double time = (n - half_size) + 0.5;
    double xx = 2.0 * cutoff * time;
    double sinc = (xx == 0.0) ? 1.0 : sin(M_PI * xx) / (M_PI * xx);
    f[n] = 2.0 * cutoff * wnd * sinc;
    s += f[n];
  }
  for (int n = 0; n < ks; ++n) out12[n] = (float)(f[n] / s);
}

__device__ __forceinline__ ushort f2bf(float f) {
  __hip_bfloat16 h = __float2bfloat16(f);
  return *(ushort*)&h;
}

__device__ __forceinline__ void gl_lds16(const void* g, void* l) {
  __builtin_amdgcn_global_load_lds(
      (const __attribute__((address_space(1))) unsigned int*)g,
      (__attribute__((address_space(3))) unsigned int*)l, 16, 0, 0);
}

// ---------------------------------------------------------------------------
// act2: fused upsample(x2,edge) -> snake_beta -> downsample(/2,edge).
// R5 finding: all 3 stages ~240-260us regardless of bytes (134-335MB) ->
// fixed per-block cost (~30us/generation vs ~2us work): launch/drain +
// cold staging latency + lockstep barriers across 8192 short blocks.
// R6: PERSISTENT-TILE version. 1024 blocks (=4/CU wave-slot limit), each
// walks NT=8 consecutive t-tiles with register prefetch pipeline:
//   WRITE_XS(tmpA); bar; PREFETCH(tile+1 -> tmpB); compute; store; bar; swap
// Next tile's HBM latency hides under current tile's FIR+snake VALU.
// alpha/beta exp hoisted out of the tile loop. Math identical to R5.
// TOUT=true : out bf16 transposed [B][T][C] (conv B-operand layout)
// TOUT=false: out fp32 [B][C][T] + residual (final stage), float4 epilogue
// ---------------------------------------------------------------------------
#define NSTG (64 * 74)

#define PREFETCH(T0, TMP)                                                \
  _Pragma("unroll")                                                      \
  for (int k = 0; k < 10; ++k) {                                         \
    int i = tid + k * 512;                                               \
    if (i < NSTG) {                                                      \
      int cI = i / 74, jI = i - cI * 74;                                 \
      int t = min(max((T0) - 5 + jI, 0), T - 1);                         \
      TMP[k] = (float)in[((long)(b * C + c0 + cI)) * T + t];             \
    }                                                                    \
  }

#define WRITE_XS(TMP)                                                    \
  _Pragma("unroll")                                                      \
  for (int k = 0; k < 10; ++k) {                                         \
    int i = tid + k * 512;                                               \
    if (i < NSTG) {                                                      \
      int cI = i / 74, jI = i - cI * 74;                                 \
      xs[cI * 75 + jI] = TMP[k];                                         \
    }                                                                    \
  }

template <typename TIN, bool TOUT>
__global__ __launch_bounds__(512, 4) void act2(
    const TIN* __restrict__ in, void* __restrict__ out_,
    const float* __restrict__ alpha_log, const float* __restrict__ beta_log,
    const float* __restrict__ resid, int C, int T, Filt fl)
{
  __shared__ float xs[64 * 75];  // row stride 75 (odd -> conflict-free), 74 used
  __shared__ float ys[TOUT ? 1 : 64 * 65];  // final-stage shuffle buffer
  const int NT = 8;                          // tiles per block
  const int tbase = blockIdx.x * (64 * NT);  // gridDim.x = T/(64*NT)
  const int c0 = blockIdx.y * 64;
  const int b  = blockIdx.z;
  const int tid = threadIdx.x;

  const int c  = tid & 63;
  const int tg = tid >> 6;        // 0..7
  const float a  = __expf(alpha_log[c0 + c]);
  const float rb = 1.0f / (__expf(beta_log[c0 + c]) + 1e-9f);

  float tmpA[10], tmpB[10];
  PREFETCH(tbase, tmpA);

  for (int tt = 0; tt < NT; ++tt) {
    const int t0 = tbase + tt * 64;
    WRITE_XS(tmpA);
    __syncthreads();
    if (tt + 1 < NT) { PREFETCH(t0 + 64, tmpB); }

    const int tb = t0 + tg * 8;
    float sbv[26];
    // interior <=> x[tb-5 .. tb+12] unclamped and sb indices in-range (wave-uniform)
    const bool interior = (tb >= 8) && (tb <= T - 16);
    if (interior) {
      float xv[18];
      const float* xr = xs + c * 75 + tg * 8;  // xv[m] = x[tb-5+m]
#pragma unroll
      for (int m = 0; m < 18; ++m) xv[m] = xr[m];
#pragma unroll
      for (int m = 0; m <= 12; ++m) {
        float uo = fl.f[1] * xv[m]     + fl.f[3] * xv[m + 1] + fl.f[5]  * xv[m + 2]
                 + fl.f[7] * xv[m + 3] + fl.f[9] * xv[m + 4] + fl.f[11] * xv[m + 5];
        float ue = fl.f[0] * xv[m]     + fl.f[2] * xv[m + 1] + fl.f[4]  * xv[m + 2]
                 + fl.f[6] * xv[m + 3] + fl.f[8] * xv[m + 4] + fl.f[10] * xv[m + 5];
        uo *= 2.0f; ue *= 2.0f;
        float s0 = __sinf(a * uo);
        float s1 = __sinf(a * ue);
        sbv[2 * m]     = uo + rb * s0 * s0;
        sbv[2 * m + 1] = ue + rb * s1 * s1;
      }
    } else {
      const float* xr = xs + c * 75;  // xr[idx] = x[clamp(t0-5+idx)]
#pragma unroll
      for (int j = 0; j < 26; ++j) {
        int p = 2 * tb - 5 + j;
        int pc = min(max(p, 0), 2 * T - 1);
        float up;
        if (pc & 1) {
          int q = (pc - 1) >> 1;
          int base = q - t0 + 3;  // x[q-2]
          up = fl.f[1] * xr[base]     + fl.f[3] * xr[base + 1] + fl.f[5]  * xr[base + 2]
             + fl.f[7] * xr[base + 3] + fl.f[9] * xr[base + 4] + fl.f[11] * xr[base + 5];
        } else {
          int q = pc >> 1;
          int base = q - t0 + 2;  // x[q-3]
          up = fl.f[0] * xr[base]     + fl.f[2] * xr[base + 1] + fl.f[4]  * xr[base + 2]
             + fl.f[6] * xr[base + 3] + fl.f[8] * xr[base + 4] + fl.f[10] * xr[base + 5];
        }
        up *= 2.0f;
        float s = __sinf(a * up);
        sbv[j] = up + rb * s * s;
      }
    }

    float acc[8];
#pragma unroll
    for (int i = 0; i < 8; ++i) {
      float s = 0.0f;
#pragma unroll
      for (int u = 0; u < 12; ++u) s += fl.f[u] * sbv[2 * i + u];
      acc[i] = s;
    }

    if constexpr (TOUT) {
      __hip_bfloat16* out = (__hip_bfloat16*)out_;
#pragma unroll
      for (int i = 0; i < 8; ++i)  // lanes = 64 consecutive c -> 128B/instr
        out[((long)b * T + tb + i) * C + c0 + c] = __float2bfloat16(acc[i]);
      __syncthreads();  // all xs reads done; next tile may overwrite
    } else {
      float* out = (float*)out_;
      // Hoist resid loads: independent of ys, hide latency under the shuffle.
      const int cc0 = tid >> 4,   tq0 = (tid & 15) * 4;
      const int cc1 = cc0 + 32,   tq1 = tq0;      // i = tid + 512
      const long o0 = ((long)(b * C + c0 + cc0)) * T + t0 + tq0;
      const long o1 = ((long)(b * C + c0 + cc1)) * T + t0 + tq1;
      const float4 r0 = *(const float4*)(resid + o0);
      const float4 r1 = *(const float4*)(resid + o1);
#pragma unroll
      for (int i = 0; i < 8; ++i) ys[c * 65 + tg * 8 + i] = acc[i];
      __syncthreads();  // ys ready
      float4 v0, v1;
      v0.x = ys[cc0 * 65 + tq0]     + r0.x;
      v0.y = ys[cc0 * 65 + tq0 + 1] + r0.y;
      v0.z = ys[cc0 * 65 + tq0 + 2] + r0.z;
      v0.w = ys[cc0 * 65 + tq0 + 3] + r0.w;
      v1.x = ys[cc1 * 65 + tq1]     + r1.x;
      v1.y = ys[cc1 * 65 + tq1 + 1] + r1.y;
      v1.z = ys[cc1 * 65 + tq1 + 2] + r1.z;
      v1.w = ys[cc1 * 65 + tq1 + 3] + r1.w;
      *(float4*)(out + o0) = v0;
      *(float4*)(out + o1) = v1;
      __syncthreads();  // xs+ys consumed; next tile may overwrite
    }

#pragma unroll
    for (int k = 0; k < 10; ++k) tmpA[k] = tmpB[k];
  }
}

// ---------------------------------------------------------------------------
// Weight pre-conversion: w fp32 [co][ci][3] -> bf16 [d][co][ci]
// ---------------------------------------------------------------------------
__global__ __launch_bounds__(256) void wconv(
    const float* __restrict__ w, ushort* __restrict__ wbf, int C)
{
  int idx = blockIdx.x * 256 + threadIdx.x;
  int total = 3 * C * C;
  if (idx >= total) return;
  int d = idx / (C * C);
  int r = idx - d * C * C;          // co*C + ci
  wbf[idx] = f2bf(w[(long)r * 3 + d]);
}

// ---------------------------------------------------------------------------
// conv_mfma: out[b,co,t] = bias[co] + sum_{ci,d} w[co,ci,d]*in[b,ci,t-1+d]
// (zero pad). Implicit GEMM via mfma_f32_16x16x32_bf16, tap-decomposed.
// Staging pure 16B global_load_lds (full waves, wave-uniform LDS base);
// halo rows (t0-1, t0+NTC) via 8 bounds-checked ds_writes.
// ---------------------------------------------------------------------------
#define MT 64
#define NTC 256
#define BK 32

__global__ __launch_bounds__(256) void conv_mfma(
    const __hip_bfloat16* __restrict__ inT,  // [B][T][C] bf16
    const ushort* __restrict__ wbf,          // [3][C(co)][C(ci)] bf16
    const float* __restrict__ bias,
    __hip_bfloat16* __restrict__ out,        // [B][C][T] bf16
    int C, int T)
{
  __shared__ ushort wl[3][MT][BK];           // slot g=((d*64+co)*4+seg) at byte g*16
  __shared__ ushort xs[NTC + 2][BK];         // slot g=(tl*4+seg) at byte g*16
  const int t0  = blockIdx.x * NTC;
  const int co0 = blockIdx.y * MT;
  const int b   = blockIdx.z;
  const int tid  = threadIdx.x;
  const int lane = tid & 63;
  const int wave = tid >> 6;
  const int ln15 = lane & 15;
  const int quad = lane >> 4;
  const ushort* inU = (const ushort*)inT;

  f32x4 acc[4][4];
#pragma unroll
  for (int mi = 0; mi < 4; ++mi)
#pragma unroll
    for (int ni = 0; ni < 4; ++ni) acc[mi][ni] = (f32x4){0.f, 0.f, 0.f, 0.f};

  ushort* wlf = &wl[0][0][0];
  ushort* xsf = &xs[0][0];

  for (int ci0 = 0; ci0 < C; ci0 += BK) {
    __syncthreads();
    // --- weights: 768 slots of 16B, 3 full-wave iterations
#pragma unroll
    for (int it = 0; it < 3; ++it) {
      int g = it * 256 + tid;
      int d = g >> 8, co = (g >> 2) & 63, seg = g & 3;
      const ushort* gsrc = wbf + ((long)d * C + co0 + co) * C + ci0 + seg * 8;
      gl_lds16(gsrc, wlf + (size_t)(it * 256 + (tid & ~63)) * 8);
    }
    // --- input interior rows tl=1..256 (t always in-bounds): slots 4..1027
#pragma unroll
    for (int it = 0; it < 4; ++it) {
      int g = it * 256 + tid + 4;
      int tl = g >> 2, seg = g & 3;
      int t = t0 - 1 + tl;
      const ushort* gsrc = inU + ((long)b * T + t) * C + ci0 + seg * 8;
      gl_lds16(gsrc, xsf + (size_t)(it * 256 + (tid & ~63) + 4) * 8);
    }
    // --- halo rows tl=0 (t0-1) and tl=257 (t0+NTC), zero-padded
    if (tid < 8) {
      int g = (tid < 4) ? tid : (1028 + tid - 4);
      int tl = g >> 2, seg = g & 3;
      int t = t0 - 1 + tl;
      uint4 v = {0u, 0u, 0u, 0u};
      if (t >= 0 && t < T)
        v = *(const uint4*)(inU + ((long)b * T + t) * C + ci0 + seg * 8);
      *(uint4*)&xs[tl][seg * 8] = v;
    }
    __syncthreads();

#pragma unroll
    for (int d = 0; d < 3; ++d) {
      bf16x8 afr[4], bfr[4];
#pragma unroll
      for (int mi = 0; mi < 4; ++mi)
        afr[mi] = *(const bf16x8*)&wl[d][mi * 16 + ln15][quad * 8];
#pragma unroll
      for (int ni = 0; ni < 4; ++ni)
        bfr[ni] = *(const bf16x8*)&xs[wave * 64 + ni * 16 + ln15 + d][quad * 8];
#pragma unroll
      for (int mi = 0; mi < 4; ++mi)
#pragma unroll
        for (int ni = 0; ni < 4; ++ni)
          acc[mi][ni] = __builtin_amdgcn_mfma_f32_16x16x32_bf16(
              afr[mi], bfr[ni], acc[mi][ni], 0, 0, 0);
    }
  }

  // epilogue: D[m][n]: n(t)=lane&15, m(co)=quad*4+reg
#pragma unroll
  for (int mi = 0; mi < 4; ++mi) {
#pragma unroll
    for (int r = 0; r < 4; ++r) {
      int co = co0 + mi * 16 + quad * 4 + r;
      float bv = bias[co];
      long orow = ((long)(b * C + co)) * T;
#pragma unroll
      for (int ni = 0; ni < 4; ++ni) {
        int t = t0 + wave * 64 + ni * 16 + ln15;
        out[orow + t] = __float2bfloat16(acc[mi][ni][r] + bv);
      }
    }
  }
}

// ---------------------------------------------------------------------------
// Pipeline. Weight bf16 scratch lives in d_out's head (3MB), fully
// overwritten by the final act2 which writes all B*C*T floats.
// ws = 2 x 67MB bf16 ping-pong.
// ---------------------------------------------------------------------------
extern "C" void kernel_launch(void* const* d_in, const int* in_sizes, int n_in,
                              void* d_out, int out_size, void* d_ws, size_t ws_size,
                              hipStream_t stream) {
  const float* x      = (const float*)d_in[0];
  const float* w1     = (const float*)d_in[1];
  const float* b1     = (const float*)d_in[2];
  const float* w2     = (const float*)d_in[3];
  const float* b2     = (const float*)d_in[4];
  const float* alpha1 = (const float*)d_in[5];
  const float* beta1  = (const float*)d_in[6];
  const float* alpha2 = (const float*)d_in[7];
  const float* beta2  = (const float*)d_in[8];
  float* out = (float*)d_out;

  const int C = in_sizes[2];             // 512
  const long total = (long)in_sizes[0];  // B*C*T
  const int T = 8192;
  const int B = (int)(total / ((long)C * T));

  __hip_bfloat16* ws0 = (__hip_bfloat16*)d_ws;        // [B][T][C]
  __hip_bfloat16* ws1 = ws0 + (size_t)B * C * T;      // [B][C][T]
  ushort* w1bf = (ushort*)d_out;                      // scratch in out head
  ushort* w2bf = w1bf + (size_t)3 * C * C;

  Filt fl;
  compute_filter(fl.f);

  dim3 actGrid(T / 512, C / 64, B);      // persistent tiles: NT=8 per block
  dim3 convGrid(T / NTC, C / MT, B);
  int wblocks = (3 * C * C + 255) / 256;

  wconv<<<wblocks, 256, 0, stream>>>(w1, w1bf, C);
  wconv<<<wblocks, 256, 0, stream>>>(w2, w2bf, C);
  act2<float, true><<<actGrid, 512, 0, stream>>>(x, ws0, alpha1, beta1, nullptr, C, T, fl);
  conv_mfma<<<convGrid, 256, 0, stream>>>(ws0, w1bf, b1, ws1, C, T);
  act2<__hip_bfloat16, true><<<actGrid, 512, 0, stream>>>(ws1, ws0, alpha1, beta1, nullptr, C, T, fl);
  conv_mfma<<<convGrid, 256, 0, stream>>>(ws0, w2bf, b2, ws1, C, T);
  act2<__hip_bfloat16, false><<<actGrid, 512, 0, stream>>>(ws1, out, alpha2, beta2, x, C, T, fl);
}

// Round 7
// 769.969 us; speedup vs baseline: 1.6062x; 1.6062x over previous
//
#include <hip/hip_runtime.h>
#include <hip/hip_bf16.h>
#include <math.h>

#ifndef M_PI
#define M_PI 3.14159265358979323846
#endif

typedef __attribute__((ext_vector_type(8))) short bf16x8;
typedef __attribute__((ext_vector_type(4))) float f32x4;

struct Filt { float f[12]; };

// ---------------------------------------------------------------------------
// Host-side kaiser-sinc filter (matches reference; FILT_UP == FILT_DOWN).
// ---------------------------------------------------------------------------
static double bessel_i0(double x) {
  double sum = 1.0, term = 1.0;
  for (int k = 1; k < 64; ++k) {
    term *= x / (2.0 * k);
    double t2 = term * term;
    sum += t2;
    if (t2 < 1e-22 * sum) break;
  }
  return sum;
}

static void compute_filter(float* out12) {
  const int ks = 12;
  const double cutoff = 0.25, half_width = 0.3;
  const int half_size = 6;
  double delta_f = 4.0 * half_width;
  double A = 2.285 * (half_size - 1) * M_PI * delta_f + 7.95;
  double beta;
  if (A > 50.0)       beta = 0.1102 * (A - 8.7);
  else if (A >= 21.0) beta = 0.5842 * pow(A - 21.0, 0.4) + 0.07886 * (A - 21.0);
  else                beta = 0.0;
  double i0b = bessel_i0(beta);
  double f[12], s = 0.0;
  for (int n = 0; n < ks; ++n) {
    double ratio = (n - (ks - 1) / 2.0) / ((ks - 1) / 2.0);
    double arg = 1.0 - ratio * ratio;
    double wnd = bessel_i0(beta * sqrt(arg > 0.0 ? arg : 0.0)) / i0b;
    double time = (n - half_size) + 0.5;
    double xx = 2.0 * cutoff * time;
    double sinc = (xx == 0.0) ? 1.0 : sin(M_PI * xx) / (M_PI * xx);
    f[n] = 2.0 * cutoff * wnd * sinc;
    s += f[n];
  }
  for (int n = 0; n < ks; ++n) out12[n] = (float)(f[n] / s);
}

__device__ __forceinline__ ushort f2bf(float f) {
  __hip_bfloat16 h = __float2bfloat16(f);
  return *(ushort*)&h;
}

__device__ __forceinline__ void gl_lds16(const void* g, void* l) {
  __builtin_amdgcn_global_load_lds(
      (const __attribute__((address_space(1))) unsigned int*)g,
      (__attribute__((address_space(3))) unsigned int*)l, 16, 0, 0);
}

// ---------------------------------------------------------------------------
// act2: fused upsample(x2,edge) -> snake_beta -> downsample(/2,edge).
// R6 finding: t-persistent blocks gave overlap (BW 1.4->2.1 TB/s) but the
// concurrent working set became the WHOLE tensor (335MB > L3) -> 2.4x HBM
// over-traffic -> net regression.
// R7: persist along C instead. Block = one 64-t tile, loops c-tiles 0..7
// with register prefetch pipeline (next c-tile's loads in flight under
// current tile's FIR+snake). Concurrent footprint = one c-slice (~17MB),
// L2/L3-resident like R5, overlap like R6. t0 wave-uniform for all tiles.
// Staging loads VECTORIZED (float4 / 16B bf16x8; window [t0-8,t0+72), 80
// elems, LDS row stride 81 = odd -> conflict-free scalar compute reads).
// Edge t-blocks (x=0,127) take scalar clamped staging, wave-uniform.
// Math identity unchanged:
//   sbv[2m]   (p odd,  q=tb-3+m): 2*sum_s F[2s+1]*xv[m+s]
//   sbv[2m+1] (p even, q=tb-2+m): 2*sum_s F[2s]  *xv[m+s]
//   acc[i] = sum_u F[u]*sbv[2i+u]
// TOUT=true : out bf16 transposed [B][T][C] (conv B-operand layout)
// TOUT=false: out fp32 [B][C][T] + residual (final stage), float4 epilogue
// ---------------------------------------------------------------------------
template <typename TIN, bool TOUT>
__global__ __launch_bounds__(512, 4) void act2(
    const TIN* __restrict__ in, void* __restrict__ out_,
    const float* __restrict__ alpha_log, const float* __restrict__ beta_log,
    const float* __restrict__ resid, int C, int T, Filt fl)
{
  __shared__ float xs[64 * 81];             // 80 used/row; stride 81 odd
  __shared__ float ys[TOUT ? 1 : 64 * 65];  // final-stage shuffle buffer
  const int t0 = blockIdx.x * 64;           // fixed per block
  const int b  = blockIdx.z;
  const int tid = threadIdx.x;
  const int c  = tid & 63;
  const int tg = tid >> 6;                  // 0..7 (wave index)
  const bool tEdge = (t0 < 8) || (t0 + 72 > T);   // block-uniform
  constexpr bool F32 = (sizeof(TIN) == 4);
  constexpr int NREG = F32 ? 3 : 2;

  float4 tA[NREG], tB[NREG];

  // ---- staging helpers: window j in [0,80), xs[cI][j] = x[clamp(t0-8+j)]
  auto prefetch = [&](int cb, float4* tt) {
    if constexpr (F32) {
#pragma unroll
      for (int k = 0; k < 3; ++k) {              // 1280 float4 chunks
        int i = tid + k * 512;
        if (i < 1280) {
          int cI = i / 20, jc = i - cI * 20;
          const float* row = (const float*)in + (long)(b * C + cb + cI) * T;
          if (!tEdge) {
            tt[k] = *(const float4*)(row + t0 - 8 + 4 * jc);
          } else {
            float* e = (float*)&tt[k];
#pragma unroll
            for (int q = 0; q < 4; ++q) {
              int t = min(max(t0 - 8 + 4 * jc + q, 0), T - 1);
              e[q] = row[t];
            }
          }
        }
      }
    } else {
      const ushort* inU = (const ushort*)in;
#pragma unroll
      for (int k = 0; k < 2; ++k) {              // 640 bf16x8 chunks
        int i = tid + k * 512;
        if (i < 640) {
          int cI = i / 10, jc = i - cI * 10;
          const ushort* row = inU + (long)(b * C + cb + cI) * T;
          if (!tEdge) {
            tt[k] = *(const float4*)(row + t0 - 8 + 8 * jc);
          } else {
            ushort* e = (ushort*)&tt[k];
#pragma unroll
            for (int q = 0; q < 8; ++q) {
              int t = min(max(t0 - 8 + 8 * jc + q, 0), T - 1);
              e[q] = row[t];
            }
          }
        }
      }
    }
  };

  auto writeXs = [&](const float4* tt) {
    if constexpr (F32) {
#pragma unroll
      for (int k = 0; k < 3; ++k) {
        int i = tid + k * 512;
        if (i < 1280) {
          int cI = i / 20, jc = i - cI * 20;
          const float* e = (const float*)&tt[k];
#pragma unroll
          for (int q = 0; q < 4; ++q) xs[cI * 81 + 4 * jc + q] = e[q];
        }
      }
    } else {
#pragma unroll
      for (int k = 0; k < 2; ++k) {
        int i = tid + k * 512;
        if (i < 640) {
          int cI = i / 10, jc = i - cI * 10;
          const ushort* e = (const ushort*)&tt[k];
#pragma unroll
          for (int q = 0; q < 8; ++q)
            xs[cI * 81 + 8 * jc + q] = __uint_as_float((unsigned)e[q] << 16);
        }
      }
    }
  };

  prefetch(0, tA);
  float aRaw = alpha_log[c];
  float bRaw = beta_log[c];

  for (int cc = 0; cc < C; cc += 64) {
    writeXs(tA);
    __syncthreads();
    const bool more = (cc + 64 < C);
    if (more) prefetch(cc + 64, tB);       // in flight under compute
    const float a  = __expf(aRaw);
    const float rb = 1.0f / (__expf(bRaw) + 1e-9f);
    if (more) { aRaw = alpha_log[cc + 64 + c]; bRaw = beta_log[cc + 64 + c]; }

    const int tb = t0 + tg * 8;
    float sbv[26];
    const bool interior = (tb >= 8) && (tb <= T - 16);  // wave-uniform
    if (interior) {
      float xv[18];
      const float* xr = xs + c * 81 + tg * 8 + 3;  // xv[m] = x[tb-5+m]
#pragma unroll
      for (int m = 0; m < 18; ++m) xv[m] = xr[m];
#pragma unroll
      for (int m = 0; m <= 12; ++m) {
        float uo = fl.f[1] * xv[m]     + fl.f[3] * xv[m + 1] + fl.f[5]  * xv[m + 2]
                 + fl.f[7] * xv[m + 3] + fl.f[9] * xv[m + 4] + fl.f[11] * xv[m + 5];
        float ue = fl.f[0] * xv[m]     + fl.f[2] * xv[m + 1] + fl.f[4]  * xv[m + 2]
                 + fl.f[6] * xv[m + 3] + fl.f[8] * xv[m + 4] + fl.f[10] * xv[m + 5];
        uo *= 2.0f; ue *= 2.0f;
        float s0 = __sinf(a * uo);
        float s1 = __sinf(a * ue);
        sbv[2 * m]     = uo + rb * s0 * s0;
        sbv[2 * m + 1] = ue + rb * s1 * s1;
      }
    } else {
      const float* xr = xs + c * 81;  // xr[idx] = x[clamp(t0-8+idx)]
#pragma unroll
      for (int j = 0; j < 26; ++j) {
        int p = 2 * tb - 5 + j;
        int pc = min(max(p, 0), 2 * T - 1);
        float up;
        if (pc & 1) {
          int q = (pc - 1) >> 1;
          int base = q - t0 + 6;  // x[q-2]
          up = fl.f[1] * xr[base]     + fl.f[3] * xr[base + 1] + fl.f[5]  * xr[base + 2]
             + fl.f[7] * xr[base + 3] + fl.f[9] * xr[base + 4] + fl.f[11] * xr[base + 5];
        } else {
          int q = pc >> 1;
          int base = q - t0 + 5;  // x[q-3]
          up = fl.f[0] * xr[base]     + fl.f[2] * xr[base + 1] + fl.f[4]  * xr[base + 2]
             + fl.f[6] * xr[base + 3] + fl.f[8] * xr[base + 4] + fl.f[10] * xr[base + 5];
        }
        up *= 2.0f;
        float s = __sinf(a * up);
        sbv[j] = up + rb * s * s;
      }
    }

    float acc[8];
#pragma unroll
    for (int i = 0; i < 8; ++i) {
      float s = 0.0f;
#pragma unroll
      for (int u = 0; u < 12; ++u) s += fl.f[u] * sbv[2 * i + u];
      acc[i] = s;
    }

    if constexpr (TOUT) {
      __hip_bfloat16* out = (__hip_bfloat16*)out_;
#pragma unroll
      for (int i = 0; i < 8; ++i)  // lanes = 64 consecutive c -> 128B/instr
        out[((long)b * T + tb + i) * C + cc + c] = __float2bfloat16(acc[i]);
    } else {
      float* out = (float*)out_;
      // resid loads issued early: independent of ys, hide under the shuffle
      const int rc0 = tid >> 4, tq = (tid & 15) * 4;
      const int rc1 = rc0 + 32;
      const long o0 = ((long)(b * C + cc + rc0)) * T + t0 + tq;
      const long o1 = ((long)(b * C + cc + rc1)) * T + t0 + tq;
      const float4 r0 = *(const float4*)(resid + o0);
      const float4 r1 = *(const float4*)(resid + o1);
#pragma unroll
      for (int i = 0; i < 8; ++i) ys[c * 65 + tg * 8 + i] = acc[i];
      __syncthreads();  // ys ready
      float4 v0, v1;
      v0.x = ys[rc0 * 65 + tq]     + r0.x;
      v0.y = ys[rc0 * 65 + tq + 1] + r0.y;
      v0.z = ys[rc0 * 65 + tq + 2] + r0.z;
      v0.w = ys[rc0 * 65 + tq + 3] + r0.w;
      v1.x = ys[rc1 * 65 + tq]     + r1.x;
      v1.y = ys[rc1 * 65 + tq + 1] + r1.y;
      v1.z = ys[rc1 * 65 + tq + 2] + r1.z;
      v1.w = ys[rc1 * 65 + tq + 3] + r1.w;
      *(float4*)(out + o0) = v0;
      *(float4*)(out + o1) = v1;
    }

    __syncthreads();  // xs (+ys) consumed; next tile may overwrite
    if (more) {
#pragma unroll
      for (int k = 0; k < NREG; ++k) tA[k] = tB[k];
    }
  }
}

// ---------------------------------------------------------------------------
// Weight pre-conversion: w fp32 [co][ci][3] -> bf16 [d][co][ci]
// ---------------------------------------------------------------------------
__global__ __launch_bounds__(256) void wconv(
    const float* __restrict__ w, ushort* __restrict__ wbf, int C)
{
  int idx = blockIdx.x * 256 + threadIdx.x;
  int total = 3 * C * C;
  if (idx >= total) return;
  int d = idx / (C * C);
  int r = idx - d * C * C;          // co*C + ci
  wbf[idx] = f2bf(w[(long)r * 3 + d]);
}

// ---------------------------------------------------------------------------
// conv_mfma: out[b,co,t] = bias[co] + sum_{ci,d} w[co,ci,d]*in[b,ci,t-1+d]
// (zero pad). Implicit GEMM via mfma_f32_16x16x32_bf16, tap-decomposed.
// Staging pure 16B global_load_lds (full waves, wave-uniform LDS base);
// halo rows (t0-1, t0+NTC) via 8 bounds-checked ds_writes.
// ---------------------------------------------------------------------------
#define MT 64
#define NTC 256
#define BK 32

__global__ __launch_bounds__(256) void conv_mfma(
    const __hip_bfloat16* __restrict__ inT,  // [B][T][C] bf16
    const ushort* __restrict__ wbf,          // [3][C(co)][C(ci)] bf16
    const float* __restrict__ bias,
    __hip_bfloat16* __restrict__ out,        // [B][C][T] bf16
    int C, int T)
{
  __shared__ ushort wl[3][MT][BK];           // slot g=((d*64+co)*4+seg) at byte g*16
  __shared__ ushort xs[NTC + 2][BK];         // slot g=(tl*4+seg) at byte g*16
  const int t0  = blockIdx.x * NTC;
  const int co0 = blockIdx.y * MT;
  const int b   = blockIdx.z;
  const int tid  = threadIdx.x;
  const int lane = tid & 63;
  const int wave = tid >> 6;
  const int ln15 = lane & 15;
  const int quad = lane >> 4;
  const ushort* inU = (const ushort*)inT;

  f32x4 acc[4][4];
#pragma unroll
  for (int mi = 0; mi < 4; ++mi)
#pragma unroll
    for (int ni = 0; ni < 4; ++ni) acc[mi][ni] = (f32x4){0.f, 0.f, 0.f, 0.f};

  ushort* wlf = &wl[0][0][0];
  ushort* xsf = &xs[0][0];

  for (int ci0 = 0; ci0 < C; ci0 += BK) {
    __syncthreads();
    // --- weights: 768 slots of 16B, 3 full-wave iterations
#pragma unroll
    for (int it = 0; it < 3; ++it) {
      int g = it * 256 + tid;
      int d = g >> 8, co = (g >> 2) & 63, seg = g & 3;
      const ushort* gsrc = wbf + ((long)d * C + co0 + co) * C + ci0 + seg * 8;
      gl_lds16(gsrc, wlf + (size_t)(it * 256 + (tid & ~63)) * 8);
    }
    // --- input interior rows tl=1..256 (t always in-bounds): slots 4..1027
#pragma unroll
    for (int it = 0; it < 4; ++it) {
      int g = it * 256 + tid + 4;
      int tl = g >> 2, seg = g & 3;
      int t = t0 - 1 + tl;
      const ushort* gsrc = inU + ((long)b * T + t) * C + ci0 + seg * 8;
      gl_lds16(gsrc, xsf + (size_t)(it * 256 + (tid & ~63) + 4) * 8);
    }
    // --- halo rows tl=0 (t0-1) and tl=257 (t0+NTC), zero-padded
    if (tid < 8) {
      int g = (tid < 4) ? tid : (1028 + tid - 4);
      int tl = g >> 2, seg = g & 3;
      int t = t0 - 1 + tl;
      uint4 v = {0u, 0u, 0u, 0u};
      if (t >= 0 && t < T)
        v = *(const uint4*)(inU + ((long)b * T + t) * C + ci0 + seg * 8);
      *(uint4*)&xs[tl][seg * 8] = v;
    }
    __syncthreads();

#pragma unroll
    for (int d = 0; d < 3; ++d) {
      bf16x8 afr[4], bfr[4];
#pragma unroll
      for (int mi = 0; mi < 4; ++mi)
        afr[mi] = *(const bf16x8*)&wl[d][mi * 16 + ln15][quad * 8];
#pragma unroll
      for (int ni = 0; ni < 4; ++ni)
        bfr[ni] = *(const bf16x8*)&xs[wave * 64 + ni * 16 + ln15 + d][quad * 8];
#pragma unroll
      for (int mi = 0; mi < 4; ++mi)
#pragma unroll
        for (int ni = 0; ni < 4; ++ni)
          acc[mi][ni] = __builtin_amdgcn_mfma_f32_16x16x32_bf16(
              afr[mi], bfr[ni], acc[mi][ni], 0, 0, 0);
    }
  }

  // epilogue: D[m][n]: n(t)=lane&15, m(co)=quad*4+reg
#pragma unroll
  for (int mi = 0; mi < 4; ++mi) {
#pragma unroll
    for (int r = 0; r < 4; ++r) {
      int co = co0 + mi * 16 + quad * 4 + r;
      float bv = bias[co];
      long orow = ((long)(b * C + co)) * T;
#pragma unroll
      for (int ni = 0; ni < 4; ++ni) {
        int t = t0 + wave * 64 + ni * 16 + ln15;
        out[orow + t] = __float2bfloat16(acc[mi][ni][r] + bv);
      }
    }
  }
}

// ---------------------------------------------------------------------------
// Pipeline. Weight bf16 scratch lives in d_out's head (3MB), fully
// overwritten by the final act2 which writes all B*C*T floats.
// ws = 2 x 67MB bf16 ping-pong.
// ---------------------------------------------------------------------------
extern "C" void kernel_launch(void* const* d_in, const int* in_sizes, int n_in,
                              void* d_out, int out_size, void* d_ws, size_t ws_size,
                              hipStream_t stream) {
  const float* x      = (const float*)d_in[0];
  const float* w1     = (const float*)d_in[1];
  const float* b1     = (const float*)d_in[2];
  const float* w2     = (const float*)d_in[3];
  const float* b2     = (const float*)d_in[4];
  const float* alpha1 = (const float*)d_in[5];
  const float* beta1  = (const float*)d_in[6];
  const float* alpha2 = (const float*)d_in[7];
  const float* beta2  = (const float*)d_in[8];
  float* out = (float*)d_out;

  const int C = in_sizes[2];             // 512
  const long total = (long)in_sizes[0];  // B*C*T
  const int T = 8192;
  const int B = (int)(total / ((long)C * T));

  __hip_bfloat16* ws0 = (__hip_bfloat16*)d_ws;        // [B][T][C]
  __hip_bfloat16* ws1 = ws0 + (size_t)B * C * T;      // [B][C][T]
  ushort* w1bf = (ushort*)d_out;                      // scratch in out head
  ushort* w2bf = w1bf + (size_t)3 * C * C;

  Filt fl;
  compute_filter(fl.f);

  dim3 actGrid(T / 64, 1, B);            // c-persistent: loop c-tiles inside
  dim3 convGrid(T / NTC, C / MT, B);
  int wblocks = (3 * C * C + 255) / 256;

  wconv<<<wblocks, 256, 0, stream>>>(w1, w1bf, C);
  wconv<<<wblocks, 256, 0, stream>>>(w2, w2bf, C);
  act2<float, true><<<actGrid, 512, 0, stream>>>(x, ws0, alpha1, beta1, nullptr, C, T, fl);
  conv_mfma<<<convGrid, 256, 0, stream>>>(ws0, w1bf, b1, ws1, C, T);
  act2<__hip_bfloat16, true><<<actGrid, 512, 0, stream>>>(ws1, ws0, alpha1, beta1, nullptr, C, T, fl);
  conv_mfma<<<convGrid, 256, 0, stream>>>(ws0, w2bf, b2, ws1, C, T);
  act2<__hip_bfloat16, false><<<actGrid, 512, 0, stream>>>(ws1, out, alpha2, beta2, x, C, T, fl);
}

// Round 9
// 768.108 us; speedup vs baseline: 1.6101x; 1.0024x over previous
//
#include <hip/hip_runtime.h>
#include <hip/hip_bf16.h>
#include <math.h>

#ifndef M_PI
#define M_PI 3.14159265358979323846
#endif

typedef __attribute__((ext_vector_type(8))) short bf16x8;
typedef __attribute__((ext_vector_type(4))) float f32x4;

struct Filt { float f[12]; };

// ---------------------------------------------------------------------------
// Host-side kaiser-sinc filter (matches reference; FILT_UP == FILT_DOWN).
// ---------------------------------------------------------------------------
static double bessel_i0(double x) {
  double sum = 1.0, term = 1.0;
  for (int k = 1; k < 64; ++k) {
    term *= x / (2.0 * k);
    double t2 = term * term;
    sum += t2;
    if (t2 < 1e-22 * sum) break;
  }
  return sum;
}

static void compute_filter(float* out12) {
  const int ks = 12;
  const double cutoff = 0.25, half_width = 0.3;
  const int half_size = 6;
  double delta_f = 4.0 * half_width;
  double A = 2.285 * (half_size - 1) * M_PI * delta_f + 7.95;
  double beta;
  if (A > 50.0)       beta = 0.1102 * (A - 8.7);
  else if (A >= 21.0) beta = 0.5842 * pow(A - 21.0, 0.4) + 0.07886 * (A - 21.0);
  else                beta = 0.0;
  double i0b = bessel_i0(beta);
  double f[12], s = 0.0;
  for (int n = 0; n < ks; ++n) {
    double ratio = (n - (ks - 1) / 2.0) / ((ks - 1) / 2.0);
    double arg = 1.0 - ratio * ratio;
    double wnd = bessel_i0(beta * sqrt(arg > 0.0 ? arg : 0.0)) / i0b;
    double time = (n - half_size) + 0.5;
    double xx = 2.0 * cutoff * time;
    double sinc = (xx == 0.0) ? 1.0 : sin(M_PI * xx) / (M_PI * xx);
    f[n] = 2.0 * cutoff * wnd * sinc;
    s += f[n];
  }
  for (int n = 0; n < ks; ++n) out12[n] = (float)(f[n] / s);
}

__device__ __forceinline__ ushort f2bf(float f) {
  __hip_bfloat16 h = __float2bfloat16(f);
  return *(ushort*)&h;
}

__device__ __forceinline__ void gl_lds16(const void* g, void* l) {
  __builtin_amdgcn_global_load_lds(
      (const __attribute__((address_space(1))) unsigned int*)g,
      (__attribute__((address_space(3))) unsigned int*)l, 16, 0, 0);
}

// LDS-only barrier: drains lgkmcnt but leaves global loads/stores (vmcnt)
// in flight across the barrier. __syncthreads() would emit
// s_waitcnt vmcnt(0) lgkmcnt(0) and kill the prefetch/store overlap.
__device__ __forceinline__ void bar_lgkm() {
  asm volatile("s_waitcnt lgkmcnt(0)" ::: "memory");
  __builtin_amdgcn_s_barrier();
}

// ---------------------------------------------------------------------------
// act2: fused upsample(x2,edge) -> snake_beta -> downsample(/2,edge).
// R7: c-persistent blocks (one 64-t tile, loop c-tiles) = locality + reg
// prefetch pipeline. Passed at 770us; BW capped at 2.46 TB/s with VALU 30%.
// R8: __syncthreads drains vmcnt(0) [HIP-compiler] -> every c-iter barrier
// waited for next-tile prefetch loads AND output stores. Replace all act2
// loop barriers with lgkmcnt(0)+raw s_barrier (LDS ordering only); prefetch
// loads and out stores now stay in flight across iterations.
// Math identity unchanged (verified R7):
//   sbv[2m]   (p odd,  q=tb-3+m): 2*sum_s F[2s+1]*xv[m+s]
//   sbv[2m+1] (p even, q=tb-2+m): 2*sum_s F[2s]  *xv[m+s]
//   acc[i] = sum_u F[u]*sbv[2i+u]
// TOUT=true : out bf16 transposed [B][T][C] (conv B-operand layout)
// TOUT=false: out fp32 [B][C][T] + residual (final stage), float4 epilogue
// ---------------------------------------------------------------------------
template <typename TIN, bool TOUT>
__global__ __launch_bounds__(512, 4) void act2(
    const TIN* __restrict__ in, void* __restrict__ out_,
    const float* __restrict__ alpha_log, const float* __restrict__ beta_log,
    const float* __restrict__ resid, int C, int T, Filt fl)
{
  __shared__ float xs[64 * 81];             // 80 used/row; stride 81 odd
  __shared__ float ys[TOUT ? 1 : 64 * 65];  // final-stage shuffle buffer
  const int t0 = blockIdx.x * 64;           // fixed per block
  const int b  = blockIdx.z;
  const int tid = threadIdx.x;
  const int c  = tid & 63;
  const int tg = tid >> 6;                  // 0..7 (wave index)
  const bool tEdge = (t0 < 8) || (t0 + 72 > T);   // block-uniform
  constexpr bool F32 = (sizeof(TIN) == 4);
  constexpr int NREG = F32 ? 3 : 2;

  float4 tA[NREG], tB[NREG];

  // ---- staging helpers: window j in [0,80), xs[cI][j] = x[clamp(t0-8+j)]
  auto prefetch = [&](int cb, float4* tt) {
    if constexpr (F32) {
#pragma unroll
      for (int k = 0; k < 3; ++k) {              // 1280 float4 chunks
        int i = tid + k * 512;
        if (i < 1280) {
          int cI = i / 20, jc = i - cI * 20;
          const float* row = (const float*)in + (long)(b * C + cb + cI) * T;
          if (!tEdge) {
            tt[k] = *(const float4*)(row + t0 - 8 + 4 * jc);
          } else {
            float* e = (float*)&tt[k];
#pragma unroll
            for (int q = 0; q < 4; ++q) {
              int t = min(max(t0 - 8 + 4 * jc + q, 0), T - 1);
              e[q] = row[t];
            }
          }
        }
      }
    } else {
      const ushort* inU = (const ushort*)in;
#pragma unroll
      for (int k = 0; k < 2; ++k) {              // 640 bf16x8 chunks
        int i = tid + k * 512;
        if (i < 640) {
          int cI = i / 10, jc = i - cI * 10;
          const ushort* row = inU + (long)(b * C + cb + cI) * T;
          if (!tEdge) {
            tt[k] = *(const float4*)(row + t0 - 8 + 8 * jc);
          } else {
            ushort* e = (ushort*)&tt[k];
#pragma unroll
            for (int q = 0; q < 8; ++q) {
              int t = min(max(t0 - 8 + 8 * jc + q, 0), T - 1);
              e[q] = row[t];
            }
          }
        }
      }
    }
  };

  auto writeXs = [&](const float4* tt) {
    if constexpr (F32) {
#pragma unroll
      for (int k = 0; k < 3; ++k) {
        int i = tid + k * 512;
        if (i < 1280) {
          int cI = i / 20, jc = i - cI * 20;
          const float* e = (const float*)&tt[k];
#pragma unroll
          for (int q = 0; q < 4; ++q) xs[cI * 81 + 4 * jc + q] = e[q];
        }
      }
    } else {
#pragma unroll
      for (int k = 0; k < 2; ++k) {
        int i = tid + k * 512;
        if (i < 640) {
          int cI = i / 10, jc = i - cI * 10;
          const ushort* e = (const ushort*)&tt[k];
#pragma unroll
          for (int q = 0; q < 8; ++q)
            xs[cI * 81 + 8 * jc + q] = __uint_as_float((unsigned)e[q] << 16);
        }
      }
    }
  };

  prefetch(0, tA);
  float aRaw = alpha_log[c];
  float bRaw = beta_log[c];

  for (int cc = 0; cc < C; cc += 64) {
    writeXs(tA);
    bar_lgkm();                            // xs ready (LDS only; vmcnt free)
    const bool more = (cc + 64 < C);
    if (more) prefetch(cc + 64, tB);       // in flight across barriers
    const float a  = __expf(aRaw);
    const float rb = 1.0f / (__expf(bRaw) + 1e-9f);
    if (more) { aRaw = alpha_log[cc + 64 + c]; bRaw = beta_log[cc + 64 + c]; }

    const int tb = t0 + tg * 8;
    float sbv[26];
    const bool interior = (tb >= 8) && (tb <= T - 16);  // wave-uniform
    if (interior) {
      float xv[18];
      const float* xr = xs + c * 81 + tg * 8 + 3;  // xv[m] = x[tb-5+m]
#pragma unroll
      for (int m = 0; m < 18; ++m) xv[m] = xr[m];
#pragma unroll
      for (int m = 0; m <= 12; ++m) {
        float uo = fl.f[1] * xv[m]     + fl.f[3] * xv[m + 1] + fl.f[5]  * xv[m + 2]
                 + fl.f[7] * xv[m + 3] + fl.f[9] * xv[m + 4] + fl.f[11] * xv[m + 5];
        float ue = fl.f[0] * xv[m]     + fl.f[2] * xv[m + 1] + fl.f[4]  * xv[m + 2]
                 + fl.f[6] * xv[m + 3] + fl.f[8] * xv[m + 4] + fl.f[10] * xv[m + 5];
        uo *= 2.0f; ue *= 2.0f;
        float s0 = __sinf(a * uo);
        float s1 = __sinf(a * ue);
        sbv[2 * m]     = uo + rb * s0 * s0;
        sbv[2 * m + 1] = ue + rb * s1 * s1;
      }
    } else {
      const float* xr = xs + c * 81;  // xr[idx] = x[clamp(t0-8+idx)]
#pragma unroll
      for (int j = 0; j < 26; ++j) {
        int p = 2 * tb - 5 + j;
        int pc = min(max(p, 0), 2 * T - 1);
        float up;
        if (pc & 1) {
          int q = (pc - 1) >> 1;
          int base = q - t0 + 6;  // x[q-2]
          up = fl.f[1] * xr[base]     + fl.f[3] * xr[base + 1] + fl.f[5]  * xr[base + 2]
             + fl.f[7] * xr[base + 3] + fl.f[9] * xr[base + 4] + fl.f[11] * xr[base + 5];
        } else {
          int q = pc >> 1;
          int base = q - t0 + 5;  // x[q-3]
          up = fl.f[0] * xr[base]     + fl.f[2] * xr[base + 1] + fl.f[4]  * xr[base + 2]
             + fl.f[6] * xr[base + 3] + fl.f[8] * xr[base + 4] + fl.f[10] * xr[base + 5];
        }
        up *= 2.0f;
        float s = __sinf(a * up);
        sbv[j] = up + rb * s * s;
      }
    }

    float acc[8];
#pragma unroll
    for (int i = 0; i < 8; ++i) {
      float s = 0.0f;
#pragma unroll
      for (int u = 0; u < 12; ++u) s += fl.f[u] * sbv[2 * i + u];
      acc[i] = s;
    }

    if constexpr (TOUT) {
      __hip_bfloat16* out = (__hip_bfloat16*)out_;
#pragma unroll
      for (int i = 0; i < 8; ++i)  // lanes = 64 consecutive c -> 128B/instr
        out[((long)b * T + tb + i) * C + cc + c] = __float2bfloat16(acc[i]);
    } else {
      float* out = (float*)out_;
      // resid loads issued early: independent of ys, hide under the shuffle
      const int rc0 = tid >> 4, tq = (tid & 15) * 4;
      const int rc1 = rc0 + 32;
      const long o0 = ((long)(b * C + cc + rc0)) * T + t0 + tq;
      const long o1 = ((long)(b * C + cc + rc1)) * T + t0 + tq;
      const float4 r0 = *(const float4*)(resid + o0);
      const float4 r1 = *(const float4*)(resid + o1);
#pragma unroll
      for (int i = 0; i < 8; ++i) ys[c * 65 + tg * 8 + i] = acc[i];
      bar_lgkm();                          // ys ready (LDS only)
      float4 v0, v1;
      v0.x = ys[rc0 * 65 + tq]     + r0.x;
      v0.y = ys[rc0 * 65 + tq + 1] + r0.y;
      v0.z = ys[rc0 * 65 + tq + 2] + r0.z;
      v0.w = ys[rc0 * 65 + tq + 3] + r0.w;
      v1.x = ys[rc1 * 65 + tq]     + r1.x;
      v1.y = ys[rc1 * 65 + tq + 1] + r1.y;
      v1.z = ys[rc1 * 65 + tq + 2] + r1.z;
      v1.w = ys[rc1 * 65 + tq + 3] + r1.w;
      *(float4*)(out + o0) = v0;
      *(float4*)(out + o1) = v1;
    }

    bar_lgkm();  // xs (+ys) consumed; next tile may overwrite. Stores +
                 // next-tile prefetch remain in flight (vmcnt not drained).
    if (more) {
#pragma unroll
      for (int k = 0; k < NREG; ++k) tA[k] = tB[k];
    }
  }
}

// ---------------------------------------------------------------------------
// Weight pre-conversion: w fp32 [co][ci][3] -> bf16 [d][co][ci]
// ---------------------------------------------------------------------------
__global__ __launch_bounds__(256) void wconv(
    const float* __restrict__ w, ushort* __restrict__ wbf, int C)
{
  int idx = blockIdx.x * 256 + threadIdx.x;
  int total = 3 * C * C;
  if (idx >= total) return;
  int d = idx / (C * C);
  int r = idx - d * C * C;          // co*C + ci
  wbf[idx] = f2bf(w[(long)r * 3 + d]);
}

// ---------------------------------------------------------------------------
// conv_mfma: out[b,co,t] = bias[co] + sum_{ci,d} w[co,ci,d]*in[b,ci,t-1+d]
// (zero pad). Implicit GEMM via mfma_f32_16x16x32_bf16, tap-decomposed.
// Staging pure 16B global_load_lds (full waves, wave-uniform LDS base);
// halo rows (t0-1, t0+NTC) via 8 bounds-checked ds_writes.
// R8: top-of-loop barrier relaxed to lgkm-only (epilogue/mfma ds_reads);
// the post-staging barrier keeps full __syncthreads (global_load_lds
// completion is vmcnt-tracked and must drain before fragment reads).
// ---------------------------------------------------------------------------
#define MT 64
#define NTC 256
#define BK 32

__global__ __launch_bounds__(256) void conv_mfma(
    const __hip_bfloat16* __restrict__ inT,  // [B][T][C] bf16
    const ushort* __restrict__ wbf,          // [3][C(co)][C(ci)] bf16
    const float* __restrict__ bias,
    __hip_bfloat16* __restrict__ out,        // [B][C][T] bf16
    int C, int T)
{
  __shared__ ushort wl[3][MT][BK];           // slot g=((d*64+co)*4+seg) at byte g*16
  __shared__ ushort xs[NTC + 2][BK];         // slot g=(tl*4+seg) at byte g*16
  const int t0  = blockIdx.x * NTC;
  const int co0 = blockIdx.y * MT;
  const int b   = blockIdx.z;
  const int tid  = threadIdx.x;
  const int lane = tid & 63;
  const int wave = tid >> 6;
  const int ln15 = lane & 15;
  const int quad = lane >> 4;
  const ushort* inU = (const ushort*)inT;

  f32x4 acc[4][4];
#pragma unroll
  for (int mi = 0; mi < 4; ++mi)
#pragma unroll
    for (int ni = 0; ni < 4; ++ni) acc[mi][ni] = (f32x4){0.f, 0.f, 0.f, 0.f};

  ushort* wlf = &wl[0][0][0];
  ushort* xsf = &xs[0][0];

  for (int ci0 = 0; ci0 < C; ci0 += BK) {
    bar_lgkm();   // previous iter's fragment ds_reads done; LDS reusable
    // --- weights: 768 slots of 16B, 3 full-wave iterations
#pragma unroll
    for (int it = 0; it < 3; ++it) {
      int g = it * 256 + tid;
      int d = g >> 8, co = (g >> 2) & 63, seg = g & 3;
      const ushort* gsrc = wbf + ((long)d * C + co0 + co) * C + ci0 + seg * 8;
      gl_lds16(gsrc, wlf + (size_t)(it * 256 + (tid & ~63)) * 8);
    }
    // --- input interior rows tl=1..256 (t always in-bounds): slots 4..1027
#pragma unroll
    for (int it = 0; it < 4; ++it) {
      int g = it * 256 + tid + 4;
      int tl = g >> 2, seg = g & 3;
      int t = t0 - 1 + tl;
      const ushort* gsrc = inU + ((long)b * T + t) * C + ci0 + seg * 8;
      gl_lds16(gsrc, xsf + (size_t)(it * 256 + (tid & ~63) + 4) * 8);
    }
    // --- halo rows tl=0 (t0-1) and tl=257 (t0+NTC), zero-padded
    if (tid < 8) {
      int g = (tid < 4) ? tid : (1028 + tid - 4);
      int tl = g >> 2, seg = g & 3;
      int t = t0 - 1 + tl;
      uint4 v = {0u, 0u, 0u, 0u};
      if (t >= 0 && t < T)
        v = *(const uint4*)(inU + ((long)b * T + t) * C + ci0 + seg * 8);
      *(uint4*)&xs[tl][seg * 8] = v;
    }
    __syncthreads();   // vmcnt(0): global_load_lds completion required

#pragma unroll
    for (int d = 0; d < 3; ++d) {
      bf16x8 afr[4], bfr[4];
#pragma unroll
      for (int mi = 0; mi < 4; ++mi)
        afr[mi] = *(const bf16x8*)&wl[d][mi * 16 + ln15][quad * 8];
#pragma unroll
      for (int ni = 0; ni < 4; ++ni)
        bfr[ni] = *(const bf16x8*)&xs[wave * 64 + ni * 16 + ln15 + d][quad * 8];
#pragma unroll
      for (int mi = 0; mi < 4; ++mi)
#pragma unroll
        for (int ni = 0; ni < 4; ++ni)
          acc[mi][ni] = __builtin_amdgcn_mfma_f32_16x16x32_bf16(
              afr[mi], bfr[ni], acc[mi][ni], 0, 0, 0);
    }
  }

  // epilogue: D[m][n]: n(t)=lane&15, m(co)=quad*4+reg
#pragma unroll
  for (int mi = 0; mi < 4; ++mi) {
#pragma unroll
    for (int r = 0; r < 4; ++r) {
      int co = co0 + mi * 16 + quad * 4 + r;
      float bv = bias[co];
      long orow = ((long)(b * C + co)) * T;
#pragma unroll
      for (int ni = 0; ni < 4; ++ni) {
        int t = t0 + wave * 64 + ni * 16 + ln15;
        out[orow + t] = __float2bfloat16(acc[mi][ni][r] + bv);
      }
    }
  }
}

// ---------------------------------------------------------------------------
// Pipeline. Weight bf16 scratch lives in d_out's head (3MB), fully
// overwritten by the final act2 which writes all B*C*T floats.
// ws = 2 x 67MB bf16 ping-pong.
// ---------------------------------------------------------------------------
extern "C" void kernel_launch(void* const* d_in, const int* in_sizes, int n_in,
                              void* d_out, int out_size, void* d_ws, size_t ws_size,
                              hipStream_t stream) {
  const float* x      = (const float*)d_in[0];
  const float* w1     = (const float*)d_in[1];
  const float* b1     = (const float*)d_in[2];
  const float* w2     = (const float*)d_in[3];
  const float* b2     = (const float*)d_in[4];
  const float* alpha1 = (const float*)d_in[5];
  const float* beta1  = (const float*)d_in[6];
  const float* alpha2 = (const float*)d_in[7];
  const float* beta2  = (const float*)d_in[8];
  float* out = (float*)d_out;

  const int C = in_sizes[2];             // 512
  const long total = (long)in_sizes[0];  // B*C*T
  const int T = 8192;
  const int B = (int)(total / ((long)C * T));

  __hip_bfloat16* ws0 = (__hip_bfloat16*)d_ws;        // [B][T][C]
  __hip_bfloat16* ws1 = ws0 + (size_t)B * C * T;      // [B][C][T]
  ushort* w1bf = (ushort*)d_out;                      // scratch in out head
  ushort* w2bf = w1bf + (size_t)3 * C * C;

  Filt fl;
  compute_filter(fl.f);

  dim3 actGrid(T / 64, 1, B);            // c-persistent: loop c-tiles inside
  dim3 convGrid(T / NTC, C / MT, B);
  int wblocks = (3 * C * C + 255) / 256;

  wconv<<<wblocks, 256, 0, stream>>>(w1, w1bf, C);
  wconv<<<wblocks, 256, 0, stream>>>(w2, w2bf, C);
  act2<float, true><<<actGrid, 512, 0, stream>>>(x, ws0, alpha1, beta1, nullptr, C, T, fl);
  conv_mfma<<<convGrid, 256, 0, stream>>>(ws0, w1bf, b1, ws1, C, T);
  act2<__hip_bfloat16, true><<<actGrid, 512, 0, stream>>>(ws1, ws0, alpha1, beta1, nullptr, C, T, fl);
  conv_mfma<<<convGrid, 256, 0, stream>>>(ws0, w2bf, b2, ws1, C, T);
  act2<__hip_bfloat16, false><<<actGrid, 512, 0, stream>>>(ws1, out, alpha2, beta2, x, C, T, fl);
}